// Round 10
// baseline (245.446 us; speedup 1.0000x reference)
//
#include <hip/hip_runtime.h>
#include <hip/hip_fp16.h>

#define NPTS 262144
#define NJ   24
#define NC   16
#define NG   128
#define PSZ  (NJ*NG*NG*NC)   // halfs per transposed plane
#define LSZ  (NJ*NG*NC)      // halfs per transposed line set
#define NBIN 4096

typedef _Float16 h2 __attribute__((ext_vector_type(2)));
typedef _Float16 h8 __attribute__((ext_vector_type(8)));

static __device__ __forceinline__ h8 splat8(float w) {
    _Float16 h = (_Float16)w;
    return (h8){h,h,h,h,h,h,h,h};
}

// ---- ws layout (bytes): all 16B-aligned ----
#define OFF_WSP   ((size_t)0)
#define OFF_WSL   (OFF_WSP + (size_t)3*PSZ*2)
#define OFF_OUTT  (OFF_WSL + (size_t)3*LSZ*2)                 // fp16 [J][NPTS]
#define OFF_PERM  (OFF_OUTT + (size_t)NJ*NPTS*2)              // int  [NPTS]
#define OFF_XYZS  (OFF_PERM + (size_t)NPTS*4)                 // f32  [NPTS][4]
#define OFF_HIST  (OFF_XYZS + (size_t)NPTS*16)                // int  [NBIN]
#define OFF_CUR   (OFF_HIST + (size_t)NBIN*4)                 // int  [NBIN]
#define WS_NEED   (OFF_CUR + (size_t)NBIN*4)

// -------- plane transpose, float4 reads: f32 [J][C][G][G] -> fp16 [J][G][G][C] --------
// Block: 8 y-rows x 32 lanes; lane covers 4 consecutive x. Per c-iter a wave reads
// 512B contiguous; per lane writes 4 texels x 32B = 128B contiguous.

__global__ __launch_bounds__(256) void transpose_planes_c4(
    const float* __restrict__ p0, const float* __restrict__ p1,
    const float* __restrict__ p2, _Float16* __restrict__ wsP)
{
    const int p = blockIdx.z, j = blockIdx.y;
    const int x = (threadIdx.x & 31) * 4;
    const int y = blockIdx.x * 8 + (threadIdx.x >> 5);
    const float* src = ((p == 0) ? p0 : (p == 1) ? p1 : p2)
                     + ((size_t)j * NC * NG + y) * NG + x;
    float4 v[16];
#pragma unroll
    for (int c = 0; c < NC; ++c)
        v[c] = *(const float4*)(src + (size_t)c * NG * NG);
    _Float16* dst = wsP + (size_t)p * PSZ + (size_t)((j * NG + y) * NG + x) * NC;
#pragma unroll
    for (int xx = 0; xx < 4; ++xx) {
        const float* vf = (const float*)v;   // v[c] component xx = vf[4*c+xx]
        h8 lo, hi;
#pragma unroll
        for (int c = 0; c < 8; ++c) {
            lo[c] = (_Float16)vf[4*c + xx];
            hi[c] = (_Float16)vf[4*(c+8) + xx];
        }
        *(h8*)(dst + xx*NC)     = lo;
        *(h8*)(dst + xx*NC + 8) = hi;
    }
}

__global__ __launch_bounds__(256) void transpose_lines_h(
    const float* __restrict__ l0, const float* __restrict__ l1,
    const float* __restrict__ l2, _Float16* __restrict__ wsL)
{
    const int p = blockIdx.z;
    const int idx = blockIdx.x * 256 + threadIdx.x;  // [0, NJ*NG*NC)
    const int c = idx & 15;
    const int z = (idx >> 4) & 127;
    const int j = idx >> 11;
    const float* src = (p == 0) ? l0 : (p == 1) ? l1 : l2;
    wsL[(size_t)p * LSZ + (size_t)(j * NG + z) * NC + c] =
        (_Float16)src[(j * NC + c) * NG + z];
}

// ---------------- spatial counting sort: 16^3 bins ----------------

static __device__ __forceinline__ int bin_key(float x, float y, float z) {
    const int qx = min(max((int)((x + 1.0f) * 8.0f), 0), 15);
    const int qy = min(max((int)((y + 1.0f) * 8.0f), 0), 15);
    const int qz = min(max((int)((z + 1.0f) * 8.0f), 0), 15);
    return (qx << 8) | (qy << 4) | qz;
}

__global__ __launch_bounds__(256) void hist_k(
    const float* __restrict__ xyz, int* __restrict__ hist)
{
    const int n = blockIdx.x * 256 + threadIdx.x;
    atomicAdd(&hist[bin_key(xyz[3*n], xyz[3*n+1], xyz[3*n+2])], 1);
}

__global__ __launch_bounds__(256) void scan_k(
    const int* __restrict__ hist, int* __restrict__ cursor)
{
    __shared__ int ssum[256];
    const int tid = threadIdx.x;
    int loc[16], s = 0;
#pragma unroll
    for (int k = 0; k < 16; ++k) { loc[k] = hist[tid * 16 + k]; s += loc[k]; }
    ssum[tid] = s;
    __syncthreads();
    for (int off = 1; off < 256; off <<= 1) {       // Hillis-Steele inclusive
        int v = (tid >= off) ? ssum[tid - off] : 0;
        __syncthreads();
        ssum[tid] += v;
        __syncthreads();
    }
    int run = (tid == 0) ? 0 : ssum[tid - 1];       // exclusive base
#pragma unroll
    for (int k = 0; k < 16; ++k) { cursor[tid * 16 + k] = run; run += loc[k]; }
}

__global__ __launch_bounds__(256) void scatter_k(
    const float* __restrict__ xyz, int* __restrict__ cursor,
    int* __restrict__ perm, float* __restrict__ xyzS /* [NPTS][4] */)
{
    const int n = blockIdx.x * 256 + threadIdx.x;
    const float x = xyz[3*n], y = xyz[3*n+1], z = xyz[3*n+2];
    const int pos = atomicAdd(&cursor[bin_key(x, y, z)], 1);
    perm[pos] = n;
    *(float4*)(xyzS + 4*(size_t)pos) = make_float4(x, y, z, 0.0f);
}

// ---------- main kernel v2: 1 lane/pair, 16 ch/lane, cross-plane prefetch -------------
// Round-8 retry with the diagnosed fix: explicit next-plane tap prefetch keeps
// dependent-load distance ~1 full plane of compute (round 8 had none -> latency-bound).

__global__ __launch_bounds__(256) void trisample_f_k(
    const float* __restrict__ xyzS, const float* __restrict__ Tm,
    const _Float16* __restrict__ wsP, const _Float16* __restrict__ wsL,
    _Float16* __restrict__ outT /* fp16 [J][NPTS] */)
{
    __shared__ _Float16 sL[3 * NG * NC];    // 12 KB: this block's joint line data

    // Bijective XCD swizzle: 24576 = 8*3072 -> XCD k owns joints [3k, 3k+3).
    const int sb = (blockIdx.x & 7) * 3072 + (blockIdx.x >> 3);
    const int j  = sb >> 10;                   // 1024 blocks per joint
    const int s0 = (sb & 1023) << 8;           // 256 sorted points per block

    {   // stage line data: 3 planes x 4KB
        uint4* s4 = (uint4*)sL;
#pragma unroll
        for (int k = 0; k < 3; ++k) {
            const int idx = k * 256 + threadIdx.x;
            const int p = idx >> 8, r = idx & 255;
            s4[idx] = ((const uint4*)(wsL + (size_t)p * LSZ + (size_t)j * (NG*NC)))[r];
        }
    }
    __syncthreads();

    const int s = s0 + threadIdx.x;
    const float4 pv = *(const float4*)(xyzS + 4*(size_t)s);
    const float px = pv.x, py = pv.y, pz = pv.z;
    const float* Tj = Tm + 16*j;               // uniform -> scalar loads

    float m0[3], m1[3];
    int   c0[3], c1[3];
#pragma unroll
    for (int a = 0; a < 3; ++a) {
        const float pt = fmaf(Tj[4*a+0], px,
                          fmaf(Tj[4*a+1], py,
                           fmaf(Tj[4*a+2], pz, Tj[4*a+3])));
        const float ia = fmaf(pt, 127.0f/3.0f, 63.5f);  // folded normalize+scale
        const float fa = floorf(ia);
        const int   i0 = (int)fa;
        const float w1 = ia - fa;
        m0[a] = (i0 >=  0 && i0 < NG    ) ? (1.0f - w1) : 0.0f;
        m1[a] = (i0 >= -1 && i0 < NG - 1) ? w1          : 0.0f;
        c0[a] = min(max(i0,     0), NG-1);
        c1[a] = min(max(i0 + 1, 0), NG-1);
    }

    const int M0[3] = {0,0,1}, M1[3] = {1,2,2}, MV[3] = {2,1,0};

    const _Float16* pbase[3];
    int o00[3], o01[3], o10[3], o11[3];        // tap half-element offsets
#pragma unroll
    for (int p = 0; p < 3; ++p) {
        pbase[p] = wsP + (size_t)p * PSZ + (size_t)j * (NG*NG*NC);
        const int r0 = c0[M1[p]] * (NG*NC), r1 = c1[M1[p]] * (NG*NC);
        const int q0 = c0[M0[p]] * NC,      q1 = c1[M0[p]] * NC;
        o00[p] = r0 + q0; o01[p] = r0 + q1; o10[p] = r1 + q0; o11[p] = r1 + q1;
    }

#define LOADP(dst, p) \
    dst##00a = *(const h8*)(pbase[p] + o00[p]);     \
    dst##00b = *(const h8*)(pbase[p] + o00[p] + 8); \
    dst##01a = *(const h8*)(pbase[p] + o01[p]);     \
    dst##01b = *(const h8*)(pbase[p] + o01[p] + 8); \
    dst##10a = *(const h8*)(pbase[p] + o10[p]);     \
    dst##10b = *(const h8*)(pbase[p] + o10[p] + 8); \
    dst##11a = *(const h8*)(pbase[p] + o11[p]);     \
    dst##11b = *(const h8*)(pbase[p] + o11[p] + 8);

    h8 A00a,A00b,A01a,A01b,A10a,A10b,A11a,A11b;
    h8 B00a,B00b,B01a,B01b,B10a,B10b,B11a,B11b;
    LOADP(A, 0)

    float sigA = 0.0f, sigB = 0.0f;            // two accumulators: shorter dot chain
#pragma unroll
    for (int p = 0; p < 3; ++p) {
        if (p < 2) { LOADP(B, p+1) }           // prefetch next plane (~1 plane ahead)

        const int A_ = M0[p], B_ = M1[p], V = MV[p];
        const _Float16* lp = sL + p * (NG*NC);
        const h8 u0a = *(const h8*)(lp + c0[V]*NC);
        const h8 u0b = *(const h8*)(lp + c0[V]*NC + 8);
        const h8 u1a = *(const h8*)(lp + c1[V]*NC);
        const h8 u1b = *(const h8*)(lp + c1[V]*NC + 8);

        const h8 w00 = splat8(m0[A_]*m0[B_]), w01 = splat8(m1[A_]*m0[B_]);
        const h8 w10 = splat8(m0[A_]*m1[B_]), w11 = splat8(m1[A_]*m1[B_]);
        const h8 z0  = splat8(m0[V]),         z1  = splat8(m1[V]);

        h8 t0a = A00a * w00; t0a += A01a * w01;
        h8 t1a = A10a * w10; t1a += A11a * w11;
        const h8 pfa = t0a + t1a;
        h8 t0b = A00b * w00; t0b += A01b * w01;
        h8 t1b = A10b * w10; t1b += A11b * w11;
        const h8 pfb = t0b + t1b;
        h8 lfa = u0a * z0; lfa += u1a * z1;
        h8 lfb = u0b * z0; lfb += u1b * z1;

#if __has_builtin(__builtin_amdgcn_fdot2)
#pragma unroll
        for (int q = 0; q < 4; ++q) {
            sigA = __builtin_amdgcn_fdot2((h2){pfa[2*q], pfa[2*q+1]},
                                          (h2){lfa[2*q], lfa[2*q+1]}, sigA, false);
            sigB = __builtin_amdgcn_fdot2((h2){pfb[2*q], pfb[2*q+1]},
                                          (h2){lfb[2*q], lfb[2*q+1]}, sigB, false);
        }
#else
#pragma unroll
        for (int q = 0; q < 8; ++q) {
            sigA += (float)pfa[q]*(float)lfa[q];
            sigB += (float)pfb[q]*(float)lfb[q];
        }
#endif
        if (p < 2) {
            A00a=B00a; A00b=B00b; A01a=B01a; A01b=B01b;
            A10a=B10a; A10b=B10b; A11a=B11a; A11b=B11b;
        }
    }
#undef LOADP

    outT[(size_t)j * NPTS + s] = (_Float16)fmaxf(sigA + sigB, 0.0f);  // 128B/wave
}

// ---------- proven main kernel (round 7/9, 125.7us) kept as revert target -------------

__global__ __launch_bounds__(256) void trisample_s_k(
    const float* __restrict__ xyzS, const float* __restrict__ Tm,
    const _Float16* __restrict__ wsP, const _Float16* __restrict__ wsL,
    _Float16* __restrict__ outT)
{
    __shared__ _Float16 sL[3 * NG * NC];
    const int sb = (blockIdx.x & 7) * (49152 >> 3) + (blockIdx.x >> 3);
    const int j  = sb >> 11;
    const int s0 = (sb & 2047) << 7;
    {
        uint4* s4 = (uint4*)sL;
#pragma unroll
        for (int k = 0; k < 3; ++k) {
            const int idx = k * 256 + threadIdx.x;
            const int p = idx >> 8, r = idx & 255;
            s4[idx] = ((const uint4*)(wsL + (size_t)p * LSZ + (size_t)j * (NG*NC)))[r];
        }
    }
    __syncthreads();
    const int s  = s0 + (threadIdx.x >> 1);
    const int hh = (threadIdx.x & 1) << 3;
    const float4 pv = *(const float4*)(xyzS + 4*(size_t)s);
    const float px = pv.x, py = pv.y, pz = pv.z;
    const float* Tj = Tm + 16*j;
    float m0[3], m1[3];
    int   c0[3], c1[3];
#pragma unroll
    for (int a = 0; a < 3; ++a) {
        const float pt = fmaf(Tj[4*a+0], px, fmaf(Tj[4*a+1], py, fmaf(Tj[4*a+2], pz, Tj[4*a+3])));
        const float ia = fmaf(pt, 127.0f/3.0f, 63.5f);
        const float fa = floorf(ia);
        const int   i0 = (int)fa;
        const float w1 = ia - fa;
        m0[a] = (i0 >=  0 && i0 < NG    ) ? (1.0f - w1) : 0.0f;
        m1[a] = (i0 >= -1 && i0 < NG - 1) ? w1          : 0.0f;
        c0[a] = min(max(i0, 0), NG-1);
        c1[a] = min(max(i0 + 1, 0), NG-1);
    }
    const int M0[3] = {0,0,1}, M1[3] = {1,2,2}, MV[3] = {2,1,0};
    const _Float16* pbase[3];
    int rb0[3], rb1[3], cb0[3], cb1[3];
#pragma unroll
    for (int p = 0; p < 3; ++p) {
        pbase[p] = wsP + (size_t)p * PSZ + (size_t)j * (NG*NG*NC) + hh;
        rb0[p] = c0[M1[p]] * (NG*NC);  rb1[p] = c1[M1[p]] * (NG*NC);
        cb0[p] = c0[M0[p]] * NC;       cb1[p] = c1[M0[p]] * NC;
    }
    float sigma = 0.0f;
    h8 a0 = *(const h8*)(pbase[0] + rb0[0] + cb0[0]);
    h8 a1 = *(const h8*)(pbase[0] + rb0[0] + cb1[0]);
    h8 a2 = *(const h8*)(pbase[0] + rb1[0] + cb0[0]);
    h8 a3 = *(const h8*)(pbase[0] + rb1[0] + cb1[0]);
#pragma unroll
    for (int p = 0; p < 3; ++p) {
        h8 b0, b1, b2, b3;
        if (p < 2) {
            b0 = *(const h8*)(pbase[p+1] + rb0[p+1] + cb0[p+1]);
            b1 = *(const h8*)(pbase[p+1] + rb0[p+1] + cb1[p+1]);
            b2 = *(const h8*)(pbase[p+1] + rb1[p+1] + cb0[p+1]);
            b3 = *(const h8*)(pbase[p+1] + rb1[p+1] + cb1[p+1]);
        }
        const int A = M0[p], B = M1[p], V = MV[p];
        const h8 u0 = *(const h8*)(sL + (p * NG + c0[V]) * NC + hh);
        const h8 u1 = *(const h8*)(sL + (p * NG + c1[V]) * NC + hh);
        h8 pf = a0 * splat8(m0[A] * m0[B]);
        pf += a1 * splat8(m1[A] * m0[B]);
        pf += a2 * splat8(m0[A] * m1[B]);
        pf += a3 * splat8(m1[A] * m1[B]);
        h8 lf = u0 * splat8(m0[V]);
        lf += u1 * splat8(m1[V]);
#if __has_builtin(__builtin_amdgcn_fdot2)
#pragma unroll
        for (int q = 0; q < 4; ++q) {
            sigma = __builtin_amdgcn_fdot2((h2){pf[2*q], pf[2*q+1]},
                                           (h2){lf[2*q], lf[2*q+1]}, sigma, false);
        }
#else
#pragma unroll
        for (int q = 0; q < 8; ++q) sigma += (float)pf[q] * (float)lf[q];
#endif
        if (p < 2) { a0 = b0; a1 = b1; a2 = b2; a3 = b3; }
    }
    sigma += __shfl_xor(sigma, 1);
    if (hh == 0) outT[(size_t)j * NPTS + s] = (_Float16)fmaxf(sigma, 0.0f);
}

// ---------------- finalize: out[perm[s]][j] = outT[j][s], f32 ----------------

__global__ __launch_bounds__(256) void finalize_k(
    const _Float16* __restrict__ outT, const int* __restrict__ perm,
    float* __restrict__ out)
{
    const int s = blockIdx.x * 256 + threadIdx.x;
    const int n = perm[s];
    float4 o[6];
#pragma unroll
    for (int j = 0; j < NJ; ++j)
        ((float*)o)[j] = (float)outT[(size_t)j * NPTS + s];
    float4* dst = (float4*)(out + (size_t)n * NJ);
#pragma unroll
    for (int k = 0; k < 6; ++k) dst[k] = o[k];
}

// ---------------- fallback (ws too small): round-3 scalar kernel ----------------

__global__ __launch_bounds__(256) void simple_trisample_k(
    const float* __restrict__ xyz, const float* __restrict__ Tm,
    const float* __restrict__ p0, const float* __restrict__ p1,
    const float* __restrict__ p2, const float* __restrict__ l0,
    const float* __restrict__ l1, const float* __restrict__ l2,
    float* __restrict__ out)
{
    const int tid = blockIdx.x * 256 + threadIdx.x;
    const int j = tid >> 18;
    const int n = tid & (NPTS - 1);
    const float x = xyz[3*n+0], y = xyz[3*n+1], z = xyz[3*n+2];
    const float* Tj = Tm + 16*j;
    float g[3];
#pragma unroll
    for (int a = 0; a < 3; ++a) {
        const float pt = Tj[4*a+0]*x + Tj[4*a+1]*y + Tj[4*a+2]*z + Tj[4*a+3];
        g[a] = (pt + 1.5f) * (2.0f/3.0f) - 1.0f;
    }
    const float* P[3] = {p0, p1, p2};
    const float* L[3] = {l0, l1, l2};
    const int M0[3] = {0,0,1}, M1[3] = {1,2,2}, MV[3] = {2,1,0};
    float sigma = 0.0f;
#pragma unroll
    for (int p = 0; p < 3; ++p) {
        const float ix = (g[M0[p]] + 1.0f) * 63.5f;
        const float iy = (g[M1[p]] + 1.0f) * 63.5f;
        const float iz = (g[MV[p]] + 1.0f) * 63.5f;
        const float fx = floorf(ix), fy = floorf(iy), fz = floorf(iz);
        const int x0 = (int)fx, y0 = (int)fy, z0 = (int)fz;
        const float wx1 = ix - fx, wy1 = iy - fy, wz1 = iz - fz;
        const float mx0 = (x0   >= 0 && x0   < NG) ? (1.0f - wx1) : 0.0f;
        const float mx1 = (x0+1 >= 0 && x0+1 < NG) ? wx1 : 0.0f;
        const float my0 = (y0   >= 0 && y0   < NG) ? (1.0f - wy1) : 0.0f;
        const float my1 = (y0+1 >= 0 && y0+1 < NG) ? wy1 : 0.0f;
        const float mz0 = (z0   >= 0 && z0   < NG) ? (1.0f - wz1) : 0.0f;
        const float mz1 = (z0+1 >= 0 && z0+1 < NG) ? wz1 : 0.0f;
        const int xc0 = min(max(x0,0),NG-1), xc1 = min(max(x0+1,0),NG-1);
        const int yc0 = min(max(y0,0),NG-1), yc1 = min(max(y0+1,0),NG-1);
        const int zc0 = min(max(z0,0),NG-1), zc1 = min(max(z0+1,0),NG-1);
        const float w00 = mx0*my0, w01 = mx1*my0, w10 = mx0*my1, w11 = mx1*my1;
        const int o00 = yc0*NG+xc0, o01 = yc0*NG+xc1, o10 = yc1*NG+xc0, o11 = yc1*NG+xc1;
        const float* pb = P[p] + (size_t)j * NC * NG * NG;
        const float* lb = L[p] + (size_t)j * NC * NG;
#pragma unroll 4
        for (int c = 0; c < NC; ++c) {
            const float* pc = pb + (size_t)c * NG * NG;
            const float pf = pc[o00]*w00 + pc[o01]*w01 + pc[o10]*w10 + pc[o11]*w11;
            const float* lc = lb + (size_t)c * NG;
            sigma += pf * (lc[zc0]*mz0 + lc[zc1]*mz1);
        }
    }
    out[(size_t)n * NJ + j] = fmaxf(sigma, 0.0f);
}

// ---------------- launch ----------------

extern "C" void kernel_launch(void* const* d_in, const int* in_sizes, int n_in,
                              void* d_out, int out_size, void* d_ws, size_t ws_size,
                              hipStream_t stream) {
    const float* xyz = nullptr;
    const float* Tm  = nullptr;
    const float* P[3] = {nullptr, nullptr, nullptr};
    const float* L[3] = {nullptr, nullptr, nullptr};
    int pi = 0, li = 0;
    for (int i = 0; i < n_in; ++i) {
        const int si = in_sizes[i];
        if      (si == NPTS * 3)            xyz = (const float*)d_in[i];
        else if (si == 16 * NJ)             Tm  = (const float*)d_in[i];
        else if (si == NJ * NC * NG * NG) { if (pi < 3) P[pi++] = (const float*)d_in[i]; }
        else if (si == NJ * NC * NG)      { if (li < 3) L[li++] = (const float*)d_in[i]; }
    }
    if (!xyz || !Tm || pi != 3 || li != 3) {
        xyz = (const float*)d_in[0];  Tm = (const float*)d_in[1];
        P[0] = (const float*)d_in[2]; P[1] = (const float*)d_in[3];
        P[2] = (const float*)d_in[4];
        L[0] = (const float*)d_in[5]; L[1] = (const float*)d_in[6];
        L[2] = (const float*)d_in[7];
    }
    float* out = (float*)d_out;
    char*  ws  = (char*)d_ws;

    if (ws_size >= WS_NEED) {
        _Float16* wsP   = (_Float16*)(ws + OFF_WSP);
        _Float16* wsL   = (_Float16*)(ws + OFF_WSL);
        _Float16* outT  = (_Float16*)(ws + OFF_OUTT);
        int*      perm  = (int*)     (ws + OFF_PERM);
        float*    xyzS  = (float*)   (ws + OFF_XYZS);
        int*      hist  = (int*)     (ws + OFF_HIST);
        int*      cur   = (int*)     (ws + OFF_CUR);

        hipMemsetAsync(hist, 0, (size_t)2 * NBIN * sizeof(int), stream);  // hist+cur
        transpose_planes_c4<<<dim3(NG/8, NJ, 3), 256, 0, stream>>>(P[0], P[1], P[2], wsP);
        transpose_lines_h<<<dim3(LSZ/256, 1, 3), 256, 0, stream>>>(L[0], L[1], L[2], wsL);
        hist_k<<<NPTS/256, 256, 0, stream>>>(xyz, hist);
        scan_k<<<1, 256, 0, stream>>>(hist, cur);
        scatter_k<<<NPTS/256, 256, 0, stream>>>(xyz, cur, perm, xyzS);
        trisample_f_k<<<24576, 256, 0, stream>>>(xyzS, Tm, wsP, wsL, outT);
        finalize_k<<<NPTS/256, 256, 0, stream>>>(outT, perm, out);
    } else {
        simple_trisample_k<<<(NPTS*NJ)/256, 256, 0, stream>>>(xyz, Tm, P[0], P[1], P[2],
                                                              L[0], L[1], L[2], out);
    }
}

// Round 11
// 190.486 us; speedup vs baseline: 1.2885x; 1.2885x over previous
//
#include <hip/hip_runtime.h>
#include <hip/hip_fp16.h>

#define NPTS 262144
#define NJ   24
#define NC   16
#define NG   128
#define PSZ  (NJ*NG*NG*NC)   // halfs per transposed plane
#define LSZ  (NJ*NG*NC)      // halfs per transposed line set
#define NBIN 32768           // 32^3 Morton bins

typedef _Float16 h2 __attribute__((ext_vector_type(2)));
typedef _Float16 h8 __attribute__((ext_vector_type(8)));

static __device__ __forceinline__ h8 splat8(float w) {
    _Float16 h = (_Float16)w;
    return (h8){h,h,h,h,h,h,h,h};
}

// ---- ws layout (bytes): all 16B-aligned ----
#define OFF_WSP   ((size_t)0)
#define OFF_WSL   (OFF_WSP + (size_t)3*PSZ*2)
#define OFF_OUTT  (OFF_WSL + (size_t)3*LSZ*2)                 // fp16 [J][NPTS]
#define OFF_PERM  (OFF_OUTT + (size_t)NJ*NPTS*2)              // int  [NPTS]
#define OFF_XYZS  (OFF_PERM + (size_t)NPTS*4)                 // f32  [NPTS][4]
#define OFF_HIST  (OFF_XYZS + (size_t)NPTS*16)                // int  [NBIN]
#define OFF_CUR   (OFF_HIST + (size_t)NBIN*4)                 // int  [NBIN]
#define WS_NEED   (OFF_CUR + (size_t)NBIN*4)

// -------- plane transpose (round-9 proven): f32 [J][C][G][G] -> fp16 [J][G][G][C] -----

__global__ __launch_bounds__(256) void transpose_planes_c(
    const float* __restrict__ p0, const float* __restrict__ p1,
    const float* __restrict__ p2, _Float16* __restrict__ wsP)
{
    const int p = blockIdx.z, j = blockIdx.y;
    const int x = threadIdx.x & 127;
    const int y = blockIdx.x * 2 + (threadIdx.x >> 7);
    const float* src = ((p == 0) ? p0 : (p == 1) ? p1 : p2)
                     + ((size_t)j * NC * NG + y) * NG + x;
    _Float16 v[16];
#pragma unroll
    for (int c = 0; c < NC; ++c)
        v[c] = (_Float16)src[(size_t)c * NG * NG];
    _Float16* dst = wsP + (size_t)p * PSZ + (size_t)((j * NG + y) * NG + x) * NC;
    *(h8*)dst       = (h8){v[0],v[1],v[2],v[3],v[4],v[5],v[6],v[7]};
    *(h8*)(dst + 8) = (h8){v[8],v[9],v[10],v[11],v[12],v[13],v[14],v[15]};
}

__global__ __launch_bounds__(256) void transpose_lines_h(
    const float* __restrict__ l0, const float* __restrict__ l1,
    const float* __restrict__ l2, _Float16* __restrict__ wsL)
{
    const int p = blockIdx.z;
    const int idx = blockIdx.x * 256 + threadIdx.x;  // [0, NJ*NG*NC)
    const int c = idx & 15;
    const int z = (idx >> 4) & 127;
    const int j = idx >> 11;
    const float* src = (p == 0) ? l0 : (p == 1) ? l1 : l2;
    wsL[(size_t)p * LSZ + (size_t)(j * NG + z) * NC + c] =
        (_Float16)src[(j * NC + c) * NG + z];
}

// ---------------- spatial counting sort: 32^3 Morton bins ----------------

static __device__ __forceinline__ int bin_key(float x, float y, float z) {
    const int qx = min(max((int)((x + 1.0f) * 16.0f), 0), 31);
    const int qy = min(max((int)((y + 1.0f) * 16.0f), 0), 31);
    const int qz = min(max((int)((z + 1.0f) * 16.0f), 0), 31);
    int k = 0;
#pragma unroll
    for (int b = 0; b < 5; ++b) {
        k |= (((qx >> b) & 1) << (3*b + 2))
           | (((qy >> b) & 1) << (3*b + 1))
           | (((qz >> b) & 1) << (3*b));
    }
    return k;   // 15-bit Morton code: consecutive bins are 3D-adjacent
}

__global__ __launch_bounds__(256) void hist_k(
    const float* __restrict__ xyz, int* __restrict__ hist)
{
    const int n = blockIdx.x * 256 + threadIdx.x;
    atomicAdd(&hist[bin_key(xyz[3*n], xyz[3*n+1], xyz[3*n+2])], 1);
}

// exclusive prefix over 32768 bins: 256 threads x 128 bins each
__global__ __launch_bounds__(256) void scan_k(
    const int* __restrict__ hist, int* __restrict__ cursor)
{
    __shared__ int ssum[256];
    const int tid = threadIdx.x;
    const int base = tid * 128;
    int s = 0;
    for (int k = 0; k < 128; ++k) s += hist[base + k];
    ssum[tid] = s;
    __syncthreads();
    for (int off = 1; off < 256; off <<= 1) {       // Hillis-Steele inclusive
        int v = (tid >= off) ? ssum[tid - off] : 0;
        __syncthreads();
        ssum[tid] += v;
        __syncthreads();
    }
    int run = (tid == 0) ? 0 : ssum[tid - 1];       // exclusive base
    for (int k = 0; k < 128; ++k) {
        cursor[base + k] = run;
        run += hist[base + k];
    }
}

__global__ __launch_bounds__(256) void scatter_k(
    const float* __restrict__ xyz, int* __restrict__ cursor,
    int* __restrict__ perm, float* __restrict__ xyzS /* [NPTS][4] */)
{
    const int n = blockIdx.x * 256 + threadIdx.x;
    const float x = xyz[3*n], y = xyz[3*n+1], z = xyz[3*n+2];
    const int pos = atomicAdd(&cursor[bin_key(x, y, z)], 1);
    perm[pos] = n;
    *(float4*)(xyzS + 4*(size_t)pos) = make_float4(x, y, z, 0.0f);
}

// ---------- main kernel (proven round-7/9 structure): 2 lanes/pair, 8 ch/lane ---------

__global__ __launch_bounds__(256) void trisample_s_k(
    const float* __restrict__ xyzS, const float* __restrict__ Tm,
    const _Float16* __restrict__ wsP, const _Float16* __restrict__ wsL,
    _Float16* __restrict__ outT /* fp16 [J][NPTS] */)
{
    __shared__ _Float16 sL[3 * NG * NC];    // 12 KB: this block's joint line data

    // Bijective XCD swizzle: 49152 = 8*6144 -> XCD k owns 3 contiguous joints.
    const int sb = (blockIdx.x & 7) * (49152 >> 3) + (blockIdx.x >> 3);
    const int j  = sb >> 11;                   // 2048 blocks per joint
    const int s0 = (sb & 2047) << 7;           // 128 sorted points per block

    {   // stage line data: 3 planes x 4KB
        uint4* s4 = (uint4*)sL;
#pragma unroll
        for (int k = 0; k < 3; ++k) {
            const int idx = k * 256 + threadIdx.x;
            const int p = idx >> 8, r = idx & 255;
            s4[idx] = ((const uint4*)(wsL + (size_t)p * LSZ + (size_t)j * (NG*NC)))[r];
        }
    }
    __syncthreads();

    const int s  = s0 + (threadIdx.x >> 1);
    const int hh = (threadIdx.x & 1) << 3;     // channel offset 0 or 8

    const float4 pv = *(const float4*)(xyzS + 4*(size_t)s);   // one dwordx4
    const float px = pv.x, py = pv.y, pz = pv.z;
    const float* Tj = Tm + 16*j;               // uniform within block -> scalar loads

    float m0[3], m1[3];
    int   c0[3], c1[3];
#pragma unroll
    for (int a = 0; a < 3; ++a) {
        const float pt = fmaf(Tj[4*a+0], px,
                          fmaf(Tj[4*a+1], py,
                           fmaf(Tj[4*a+2], pz, Tj[4*a+3])));
        const float ia = fmaf(pt, 127.0f/3.0f, 63.5f);  // folded normalize+scale
        const float fa = floorf(ia);
        const int   i0 = (int)fa;
        const float w1 = ia - fa;
        m0[a] = (i0 >=  0 && i0 < NG    ) ? (1.0f - w1) : 0.0f;
        m1[a] = (i0 >= -1 && i0 < NG - 1) ? w1          : 0.0f;
        c0[a] = min(max(i0,     0), NG-1);
        c1[a] = min(max(i0 + 1, 0), NG-1);
    }

    const int M0[3] = {0,0,1}, M1[3] = {1,2,2}, MV[3] = {2,1,0};

    const _Float16* pbase[3];
    int rb0[3], rb1[3], cb0[3], cb1[3];
#pragma unroll
    for (int p = 0; p < 3; ++p) {
        pbase[p] = wsP + (size_t)p * PSZ + (size_t)j * (NG*NG*NC) + hh;
        rb0[p] = c0[M1[p]] * (NG*NC);  rb1[p] = c1[M1[p]] * (NG*NC);
        cb0[p] = c0[M0[p]] * NC;       cb1[p] = c1[M0[p]] * NC;
    }

    float sigma = 0.0f;
    h8 a0 = *(const h8*)(pbase[0] + rb0[0] + cb0[0]);
    h8 a1 = *(const h8*)(pbase[0] + rb0[0] + cb1[0]);
    h8 a2 = *(const h8*)(pbase[0] + rb1[0] + cb0[0]);
    h8 a3 = *(const h8*)(pbase[0] + rb1[0] + cb1[0]);
#pragma unroll
    for (int p = 0; p < 3; ++p) {
        h8 b0, b1, b2, b3;
        if (p < 2) {
            b0 = *(const h8*)(pbase[p+1] + rb0[p+1] + cb0[p+1]);
            b1 = *(const h8*)(pbase[p+1] + rb0[p+1] + cb1[p+1]);
            b2 = *(const h8*)(pbase[p+1] + rb1[p+1] + cb0[p+1]);
            b3 = *(const h8*)(pbase[p+1] + rb1[p+1] + cb1[p+1]);
        }
        const int A = M0[p], B = M1[p], V = MV[p];
        const h8 u0 = *(const h8*)(sL + (p * NG + c0[V]) * NC + hh);
        const h8 u1 = *(const h8*)(sL + (p * NG + c1[V]) * NC + hh);

        h8 pf = a0 * splat8(m0[A] * m0[B]);
        pf += a1 * splat8(m1[A] * m0[B]);
        pf += a2 * splat8(m0[A] * m1[B]);
        pf += a3 * splat8(m1[A] * m1[B]);
        h8 lf = u0 * splat8(m0[V]);
        lf += u1 * splat8(m1[V]);

#if __has_builtin(__builtin_amdgcn_fdot2)
#pragma unroll
        for (int q = 0; q < 4; ++q) {
            const h2 va = {pf[2*q], pf[2*q+1]};
            const h2 vb = {lf[2*q], lf[2*q+1]};
            sigma = __builtin_amdgcn_fdot2(va, vb, sigma, false);
        }
#else
#pragma unroll
        for (int q = 0; q < 8; ++q)
            sigma += (float)pf[q] * (float)lf[q];
#endif
        if (p < 2) { a0 = b0; a1 = b1; a2 = b2; a3 = b3; }
    }

    sigma += __shfl_xor(sigma, 1);
    if (hh == 0)
        outT[(size_t)j * NPTS + s] = (_Float16)fmaxf(sigma, 0.0f);   // coalesced
}

// ---------------- finalize: out[perm[s]][j] = outT[j][s], f32 ----------------

__global__ __launch_bounds__(256) void finalize_k(
    const _Float16* __restrict__ outT, const int* __restrict__ perm,
    float* __restrict__ out)
{
    const int s = blockIdx.x * 256 + threadIdx.x;
    const int n = perm[s];
    float4 o[6];
#pragma unroll
    for (int j = 0; j < NJ; ++j)                       // strided-coalesced reads
        ((float*)o)[j] = (float)outT[(size_t)j * NPTS + s];
    float4* dst = (float4*)(out + (size_t)n * NJ);     // 96B contiguous, 16B-aligned
#pragma unroll
    for (int k = 0; k < 6; ++k) dst[k] = o[k];
}

// ---------------- fallback (ws too small): round-3 scalar kernel ----------------

__global__ __launch_bounds__(256) void simple_trisample_k(
    const float* __restrict__ xyz, const float* __restrict__ Tm,
    const float* __restrict__ p0, const float* __restrict__ p1,
    const float* __restrict__ p2, const float* __restrict__ l0,
    const float* __restrict__ l1, const float* __restrict__ l2,
    float* __restrict__ out)
{
    const int tid = blockIdx.x * 256 + threadIdx.x;
    const int j = tid >> 18;
    const int n = tid & (NPTS - 1);
    const float x = xyz[3*n+0], y = xyz[3*n+1], z = xyz[3*n+2];
    const float* Tj = Tm + 16*j;
    float g[3];
#pragma unroll
    for (int a = 0; a < 3; ++a) {
        const float pt = Tj[4*a+0]*x + Tj[4*a+1]*y + Tj[4*a+2]*z + Tj[4*a+3];
        g[a] = (pt + 1.5f) * (2.0f/3.0f) - 1.0f;
    }
    const float* P[3] = {p0, p1, p2};
    const float* L[3] = {l0, l1, l2};
    const int M0[3] = {0,0,1}, M1[3] = {1,2,2}, MV[3] = {2,1,0};
    float sigma = 0.0f;
#pragma unroll
    for (int p = 0; p < 3; ++p) {
        const float ix = (g[M0[p]] + 1.0f) * 63.5f;
        const float iy = (g[M1[p]] + 1.0f) * 63.5f;
        const float iz = (g[MV[p]] + 1.0f) * 63.5f;
        const float fx = floorf(ix), fy = floorf(iy), fz = floorf(iz);
        const int x0 = (int)fx, y0 = (int)fy, z0 = (int)fz;
        const float wx1 = ix - fx, wy1 = iy - fy, wz1 = iz - fz;
        const float mx0 = (x0   >= 0 && x0   < NG) ? (1.0f - wx1) : 0.0f;
        const float mx1 = (x0+1 >= 0 && x0+1 < NG) ? wx1 : 0.0f;
        const float my0 = (y0   >= 0 && y0   < NG) ? (1.0f - wy1) : 0.0f;
        const float my1 = (y0+1 >= 0 && y0+1 < NG) ? wy1 : 0.0f;
        const float mz0 = (z0   >= 0 && z0   < NG) ? (1.0f - wz1) : 0.0f;
        const float mz1 = (z0+1 >= 0 && z0+1 < NG) ? wz1 : 0.0f;
        const int xc0 = min(max(x0,0),NG-1), xc1 = min(max(x0+1,0),NG-1);
        const int yc0 = min(max(y0,0),NG-1), yc1 = min(max(y0+1,0),NG-1);
        const int zc0 = min(max(z0,0),NG-1), zc1 = min(max(z0+1,0),NG-1);
        const float w00 = mx0*my0, w01 = mx1*my0, w10 = mx0*my1, w11 = mx1*my1;
        const int o00 = yc0*NG+xc0, o01 = yc0*NG+xc1, o10 = yc1*NG+xc0, o11 = yc1*NG+xc1;
        const float* pb = P[p] + (size_t)j * NC * NG * NG;
        const float* lb = L[p] + (size_t)j * NC * NG;
#pragma unroll 4
        for (int c = 0; c < NC; ++c) {
            const float* pc = pb + (size_t)c * NG * NG;
            const float pf = pc[o00]*w00 + pc[o01]*w01 + pc[o10]*w10 + pc[o11]*w11;
            const float* lc = lb + (size_t)c * NG;
            sigma += pf * (lc[zc0]*mz0 + lc[zc1]*mz1);
        }
    }
    out[(size_t)n * NJ + j] = fmaxf(sigma, 0.0f);
}

// ---------------- launch ----------------

extern "C" void kernel_launch(void* const* d_in, const int* in_sizes, int n_in,
                              void* d_out, int out_size, void* d_ws, size_t ws_size,
                              hipStream_t stream) {
    const float* xyz = nullptr;
    const float* Tm  = nullptr;
    const float* P[3] = {nullptr, nullptr, nullptr};
    const float* L[3] = {nullptr, nullptr, nullptr};
    int pi = 0, li = 0;
    for (int i = 0; i < n_in; ++i) {
        const int si = in_sizes[i];
        if      (si == NPTS * 3)            xyz = (const float*)d_in[i];
        else if (si == 16 * NJ)             Tm  = (const float*)d_in[i];
        else if (si == NJ * NC * NG * NG) { if (pi < 3) P[pi++] = (const float*)d_in[i]; }
        else if (si == NJ * NC * NG)      { if (li < 3) L[li++] = (const float*)d_in[i]; }
    }
    if (!xyz || !Tm || pi != 3 || li != 3) {
        xyz = (const float*)d_in[0];  Tm = (const float*)d_in[1];
        P[0] = (const float*)d_in[2]; P[1] = (const float*)d_in[3];
        P[2] = (const float*)d_in[4];
        L[0] = (const float*)d_in[5]; L[1] = (const float*)d_in[6];
        L[2] = (const float*)d_in[7];
    }
    float* out = (float*)d_out;
    char*  ws  = (char*)d_ws;

    if (ws_size >= WS_NEED) {
        _Float16* wsP   = (_Float16*)(ws + OFF_WSP);
        _Float16* wsL   = (_Float16*)(ws + OFF_WSL);
        _Float16* outT  = (_Float16*)(ws + OFF_OUTT);
        int*      perm  = (int*)     (ws + OFF_PERM);
        float*    xyzS  = (float*)   (ws + OFF_XYZS);
        int*      hist  = (int*)     (ws + OFF_HIST);
        int*      cur   = (int*)     (ws + OFF_CUR);

        hipMemsetAsync(hist, 0, (size_t)2 * NBIN * sizeof(int), stream);  // hist+cur
        transpose_planes_c<<<dim3(NG/2, NJ, 3), 256, 0, stream>>>(P[0], P[1], P[2], wsP);
        transpose_lines_h<<<dim3(LSZ/256, 1, 3), 256, 0, stream>>>(L[0], L[1], L[2], wsL);
        hist_k<<<NPTS/256, 256, 0, stream>>>(xyz, hist);
        scan_k<<<1, 256, 0, stream>>>(hist, cur);
        scatter_k<<<NPTS/256, 256, 0, stream>>>(xyz, cur, perm, xyzS);
        trisample_s_k<<<49152, 256, 0, stream>>>(xyzS, Tm, wsP, wsL, outT);
        finalize_k<<<NPTS/256, 256, 0, stream>>>(outT, perm, out);
    } else {
        simple_trisample_k<<<(NPTS*NJ)/256, 256, 0, stream>>>(xyz, Tm, P[0], P[1], P[2],
                                                              L[0], L[1], L[2], out);
    }
}

// Round 12
// 181.078 us; speedup vs baseline: 1.3555x; 1.0520x over previous
//
#include <hip/hip_runtime.h>
#include <hip/hip_fp16.h>

#define NPTS 262144
#define NJ   24
#define NC   16
#define NG   128
#define PSZ  (NJ*NG*NG*NC)   // halfs per transposed plane
#define LSZ  (NJ*NG*NC)      // halfs per transposed line set
#define NBIN 32768           // 32^3 Morton bins

typedef _Float16 h2 __attribute__((ext_vector_type(2)));
typedef _Float16 h8 __attribute__((ext_vector_type(8)));

static __device__ __forceinline__ h8 splat8(float w) {
    _Float16 h = (_Float16)w;
    return (h8){h,h,h,h,h,h,h,h};
}

// ---- ws layout (bytes): all 16B-aligned ----
#define OFF_WSP   ((size_t)0)
#define OFF_WSL   (OFF_WSP + (size_t)3*PSZ*2)
#define OFF_OUTT  (OFF_WSL + (size_t)3*LSZ*2)                 // fp16 [J][NPTS]
#define OFF_PERM  (OFF_OUTT + (size_t)NJ*NPTS*2)              // int  [NPTS]
#define OFF_XYZS  (OFF_PERM + (size_t)NPTS*4)                 // f32  [NPTS][4]
#define OFF_HIST  (OFF_XYZS + (size_t)NPTS*16)                // int  [NBIN]
#define OFF_CUR   (OFF_HIST + (size_t)NBIN*4)                 // int  [NBIN]
#define WS_NEED   (OFF_CUR + (size_t)NBIN*4)

// -------- plane transpose, float2 reads: f32 [J][C][G][G] -> fp16 [J][G][G][C] --------
// Wave reads 512B contiguous per c-iter; lane writes 2 texels = 64B contiguous.

__global__ __launch_bounds__(256) void transpose_planes_c2(
    const float* __restrict__ p0, const float* __restrict__ p1,
    const float* __restrict__ p2, _Float16* __restrict__ wsP)
{
    const int p = blockIdx.z, j = blockIdx.y;
    const int x = (threadIdx.x & 63) * 2;
    const int y = blockIdx.x * 4 + (threadIdx.x >> 6);
    const float* src = ((p == 0) ? p0 : (p == 1) ? p1 : p2)
                     + ((size_t)j * NC * NG + y) * NG + x;
    float2 v[16];
#pragma unroll
    for (int c = 0; c < NC; ++c)
        v[c] = *(const float2*)(src + (size_t)c * NG * NG);
    _Float16* dst = wsP + (size_t)p * PSZ + (size_t)((j * NG + y) * NG + x) * NC;
    *(h8*)(dst)      = (h8){(_Float16)v[0].x,(_Float16)v[1].x,(_Float16)v[2].x,(_Float16)v[3].x,
                            (_Float16)v[4].x,(_Float16)v[5].x,(_Float16)v[6].x,(_Float16)v[7].x};
    *(h8*)(dst + 8)  = (h8){(_Float16)v[8].x,(_Float16)v[9].x,(_Float16)v[10].x,(_Float16)v[11].x,
                            (_Float16)v[12].x,(_Float16)v[13].x,(_Float16)v[14].x,(_Float16)v[15].x};
    *(h8*)(dst + 16) = (h8){(_Float16)v[0].y,(_Float16)v[1].y,(_Float16)v[2].y,(_Float16)v[3].y,
                            (_Float16)v[4].y,(_Float16)v[5].y,(_Float16)v[6].y,(_Float16)v[7].y};
    *(h8*)(dst + 24) = (h8){(_Float16)v[8].y,(_Float16)v[9].y,(_Float16)v[10].y,(_Float16)v[11].y,
                            (_Float16)v[12].y,(_Float16)v[13].y,(_Float16)v[14].y,(_Float16)v[15].y};
}

__global__ __launch_bounds__(256) void transpose_lines_h(
    const float* __restrict__ l0, const float* __restrict__ l1,
    const float* __restrict__ l2, _Float16* __restrict__ wsL)
{
    const int p = blockIdx.z;
    const int idx = blockIdx.x * 256 + threadIdx.x;  // [0, NJ*NG*NC)
    const int c = idx & 15;
    const int z = (idx >> 4) & 127;
    const int j = idx >> 11;
    const float* src = (p == 0) ? l0 : (p == 1) ? l1 : l2;
    wsL[(size_t)p * LSZ + (size_t)(j * NG + z) * NC + c] =
        (_Float16)src[(j * NC + c) * NG + z];
}

// ---------------- spatial counting sort: 32^3 Morton bins ----------------

static __device__ __forceinline__ int bin_key(float x, float y, float z) {
    const int qx = min(max((int)((x + 1.0f) * 16.0f), 0), 31);
    const int qy = min(max((int)((y + 1.0f) * 16.0f), 0), 31);
    const int qz = min(max((int)((z + 1.0f) * 16.0f), 0), 31);
    int k = 0;
#pragma unroll
    for (int b = 0; b < 5; ++b) {
        k |= (((qx >> b) & 1) << (3*b + 2))
           | (((qy >> b) & 1) << (3*b + 1))
           | (((qz >> b) & 1) << (3*b));
    }
    return k;   // 15-bit Morton code: consecutive bins are 3D-adjacent
}

__global__ __launch_bounds__(256) void hist_k(
    const float* __restrict__ xyz, int* __restrict__ hist)
{
    const int n = blockIdx.x * 256 + threadIdx.x;
    atomicAdd(&hist[bin_key(xyz[3*n], xyz[3*n+1], xyz[3*n+2])], 1);
}

// exclusive prefix over 32768 bins: 256 threads x 128 bins each
__global__ __launch_bounds__(256) void scan_k(
    const int* __restrict__ hist, int* __restrict__ cursor)
{
    __shared__ int ssum[256];
    const int tid = threadIdx.x;
    const int base = tid * 128;
    int s = 0;
    for (int k = 0; k < 128; ++k) s += hist[base + k];
    ssum[tid] = s;
    __syncthreads();
    for (int off = 1; off < 256; off <<= 1) {       // Hillis-Steele inclusive
        int v = (tid >= off) ? ssum[tid - off] : 0;
        __syncthreads();
        ssum[tid] += v;
        __syncthreads();
    }
    int run = (tid == 0) ? 0 : ssum[tid - 1];       // exclusive base
    for (int k = 0; k < 128; ++k) {
        cursor[base + k] = run;
        run += hist[base + k];
    }
}

__global__ __launch_bounds__(256) void scatter_k(
    const float* __restrict__ xyz, int* __restrict__ cursor,
    int* __restrict__ perm, float* __restrict__ xyzS /* [NPTS][4] */)
{
    const int n = blockIdx.x * 256 + threadIdx.x;
    const float x = xyz[3*n], y = xyz[3*n+1], z = xyz[3*n+2];
    const int pos = atomicAdd(&cursor[bin_key(x, y, z)], 1);
    perm[pos] = n;
    *(float4*)(xyzS + 4*(size_t)pos) = make_float4(x, y, z, 0.0f);
}

// ---------- main kernel v3: 2 lanes/pair, 8 chunks/block (sL staged once) -------------

__global__ __launch_bounds__(256) void trisample_m_k(
    const float* __restrict__ xyzS, const float* __restrict__ Tm,
    const _Float16* __restrict__ wsP, const _Float16* __restrict__ wsL,
    _Float16* __restrict__ outT /* fp16 [J][NPTS] */)
{
    __shared__ _Float16 sL[3 * NG * NC];    // 12 KB: this block's joint line data

    // Bijective XCD swizzle: 6144 = 8*768 -> XCD k owns joints [3k, 3k+3).
    const int sb = (blockIdx.x & 7) * 768 + (blockIdx.x >> 3);
    const int j  = sb >> 8;                    // 256 blocks per joint
    const int g0 = (sb & 255) << 10;           // 1024 sorted points per block

    {   // stage line data ONCE: 3 planes x 4KB
        uint4* s4 = (uint4*)sL;
#pragma unroll
        for (int k = 0; k < 3; ++k) {
            const int idx = k * 256 + threadIdx.x;
            const int p = idx >> 8, r = idx & 255;
            s4[idx] = ((const uint4*)(wsL + (size_t)p * LSZ + (size_t)j * (NG*NC)))[r];
        }
    }
    __syncthreads();

    const int sbase = g0 + (threadIdx.x >> 1);
    const int hh    = (threadIdx.x & 1) << 3;  // channel offset 0 or 8
    const float* Tj = Tm + 16*j;               // uniform within block -> scalar loads
    const int M0[3] = {0,0,1}, M1[3] = {1,2,2}, MV[3] = {2,1,0};

    const _Float16* pjbase[3];
#pragma unroll
    for (int p = 0; p < 3; ++p)
        pjbase[p] = wsP + (size_t)p * PSZ + (size_t)j * (NG*NG*NC) + hh;

#pragma unroll 2
    for (int ch = 0; ch < 8; ++ch) {
        const int s = sbase + (ch << 7);       // 128 pairs per chunk

        const float4 pv = *(const float4*)(xyzS + 4*(size_t)s);
        const float px = pv.x, py = pv.y, pz = pv.z;

        float m0[3], m1[3];
        int   c0[3], c1[3];
#pragma unroll
        for (int a = 0; a < 3; ++a) {
            const float pt = fmaf(Tj[4*a+0], px,
                              fmaf(Tj[4*a+1], py,
                               fmaf(Tj[4*a+2], pz, Tj[4*a+3])));
            const float ia = fmaf(pt, 127.0f/3.0f, 63.5f);  // folded normalize+scale
            const float fa = floorf(ia);
            const int   i0 = (int)fa;
            const float w1 = ia - fa;
            m0[a] = (i0 >=  0 && i0 < NG    ) ? (1.0f - w1) : 0.0f;
            m1[a] = (i0 >= -1 && i0 < NG - 1) ? w1          : 0.0f;
            c0[a] = min(max(i0,     0), NG-1);
            c1[a] = min(max(i0 + 1, 0), NG-1);
        }

        int rb0[3], rb1[3], cb0[3], cb1[3];
#pragma unroll
        for (int p = 0; p < 3; ++p) {
            rb0[p] = c0[M1[p]] * (NG*NC);  rb1[p] = c1[M1[p]] * (NG*NC);
            cb0[p] = c0[M0[p]] * NC;       cb1[p] = c1[M0[p]] * NC;
        }

        float sigma = 0.0f;
        h8 a0 = *(const h8*)(pjbase[0] + rb0[0] + cb0[0]);
        h8 a1 = *(const h8*)(pjbase[0] + rb0[0] + cb1[0]);
        h8 a2 = *(const h8*)(pjbase[0] + rb1[0] + cb0[0]);
        h8 a3 = *(const h8*)(pjbase[0] + rb1[0] + cb1[0]);
#pragma unroll
        for (int p = 0; p < 3; ++p) {
            h8 b0, b1, b2, b3;
            if (p < 2) {
                b0 = *(const h8*)(pjbase[p+1] + rb0[p+1] + cb0[p+1]);
                b1 = *(const h8*)(pjbase[p+1] + rb0[p+1] + cb1[p+1]);
                b2 = *(const h8*)(pjbase[p+1] + rb1[p+1] + cb0[p+1]);
                b3 = *(const h8*)(pjbase[p+1] + rb1[p+1] + cb1[p+1]);
            }
            const int A = M0[p], B = M1[p], V = MV[p];
            const h8 u0 = *(const h8*)(sL + (p * NG + c0[V]) * NC + hh);
            const h8 u1 = *(const h8*)(sL + (p * NG + c1[V]) * NC + hh);

            h8 pf = a0 * splat8(m0[A] * m0[B]);
            pf += a1 * splat8(m1[A] * m0[B]);
            pf += a2 * splat8(m0[A] * m1[B]);
            pf += a3 * splat8(m1[A] * m1[B]);
            h8 lf = u0 * splat8(m0[V]);
            lf += u1 * splat8(m1[V]);

#if __has_builtin(__builtin_amdgcn_fdot2)
#pragma unroll
            for (int q = 0; q < 4; ++q) {
                const h2 va = {pf[2*q], pf[2*q+1]};
                const h2 vb = {lf[2*q], lf[2*q+1]};
                sigma = __builtin_amdgcn_fdot2(va, vb, sigma, false);
            }
#else
#pragma unroll
            for (int q = 0; q < 8; ++q)
                sigma += (float)pf[q] * (float)lf[q];
#endif
            if (p < 2) { a0 = b0; a1 = b1; a2 = b2; a3 = b3; }
        }

        sigma += __shfl_xor(sigma, 1);
        if (hh == 0)
            outT[(size_t)j * NPTS + s] = (_Float16)fmaxf(sigma, 0.0f);
    }
}

// ---------- proven single-shot main kernel (round 7/9, 125.7us) kept as revert --------

__global__ __launch_bounds__(256) void trisample_s_k(
    const float* __restrict__ xyzS, const float* __restrict__ Tm,
    const _Float16* __restrict__ wsP, const _Float16* __restrict__ wsL,
    _Float16* __restrict__ outT)
{
    __shared__ _Float16 sL[3 * NG * NC];
    const int sb = (blockIdx.x & 7) * (49152 >> 3) + (blockIdx.x >> 3);
    const int j  = sb >> 11;
    const int s0 = (sb & 2047) << 7;
    {
        uint4* s4 = (uint4*)sL;
#pragma unroll
        for (int k = 0; k < 3; ++k) {
            const int idx = k * 256 + threadIdx.x;
            const int p = idx >> 8, r = idx & 255;
            s4[idx] = ((const uint4*)(wsL + (size_t)p * LSZ + (size_t)j * (NG*NC)))[r];
        }
    }
    __syncthreads();
    const int s  = s0 + (threadIdx.x >> 1);
    const int hh = (threadIdx.x & 1) << 3;
    const float4 pv = *(const float4*)(xyzS + 4*(size_t)s);
    const float px = pv.x, py = pv.y, pz = pv.z;
    const float* Tj = Tm + 16*j;
    float m0[3], m1[3];
    int   c0[3], c1[3];
#pragma unroll
    for (int a = 0; a < 3; ++a) {
        const float pt = fmaf(Tj[4*a+0], px, fmaf(Tj[4*a+1], py, fmaf(Tj[4*a+2], pz, Tj[4*a+3])));
        const float ia = fmaf(pt, 127.0f/3.0f, 63.5f);
        const float fa = floorf(ia);
        const int   i0 = (int)fa;
        const float w1 = ia - fa;
        m0[a] = (i0 >=  0 && i0 < NG    ) ? (1.0f - w1) : 0.0f;
        m1[a] = (i0 >= -1 && i0 < NG - 1) ? w1          : 0.0f;
        c0[a] = min(max(i0, 0), NG-1);
        c1[a] = min(max(i0 + 1, 0), NG-1);
    }
    const int M0[3] = {0,0,1}, M1[3] = {1,2,2}, MV[3] = {2,1,0};
    const _Float16* pbase[3];
    int rb0[3], rb1[3], cb0[3], cb1[3];
#pragma unroll
    for (int p = 0; p < 3; ++p) {
        pbase[p] = wsP + (size_t)p * PSZ + (size_t)j * (NG*NG*NC) + hh;
        rb0[p] = c0[M1[p]] * (NG*NC);  rb1[p] = c1[M1[p]] * (NG*NC);
        cb0[p] = c0[M0[p]] * NC;       cb1[p] = c1[M0[p]] * NC;
    }
    float sigma = 0.0f;
    h8 a0 = *(const h8*)(pbase[0] + rb0[0] + cb0[0]);
    h8 a1 = *(const h8*)(pbase[0] + rb0[0] + cb1[0]);
    h8 a2 = *(const h8*)(pbase[0] + rb1[0] + cb0[0]);
    h8 a3 = *(const h8*)(pbase[0] + rb1[0] + cb1[0]);
#pragma unroll
    for (int p = 0; p < 3; ++p) {
        h8 b0, b1, b2, b3;
        if (p < 2) {
            b0 = *(const h8*)(pbase[p+1] + rb0[p+1] + cb0[p+1]);
            b1 = *(const h8*)(pbase[p+1] + rb0[p+1] + cb1[p+1]);
            b2 = *(const h8*)(pbase[p+1] + rb1[p+1] + cb0[p+1]);
            b3 = *(const h8*)(pbase[p+1] + rb1[p+1] + cb1[p+1]);
        }
        const int A = M0[p], B = M1[p], V = MV[p];
        const h8 u0 = *(const h8*)(sL + (p * NG + c0[V]) * NC + hh);
        const h8 u1 = *(const h8*)(sL + (p * NG + c1[V]) * NC + hh);
        h8 pf = a0 * splat8(m0[A] * m0[B]);
        pf += a1 * splat8(m1[A] * m0[B]);
        pf += a2 * splat8(m0[A] * m1[B]);
        pf += a3 * splat8(m1[A] * m1[B]);
        h8 lf = u0 * splat8(m0[V]);
        lf += u1 * splat8(m1[V]);
#if __has_builtin(__builtin_amdgcn_fdot2)
#pragma unroll
        for (int q = 0; q < 4; ++q) {
            sigma = __builtin_amdgcn_fdot2((h2){pf[2*q], pf[2*q+1]},
                                           (h2){lf[2*q], lf[2*q+1]}, sigma, false);
        }
#else
#pragma unroll
        for (int q = 0; q < 8; ++q) sigma += (float)pf[q] * (float)lf[q];
#endif
        if (p < 2) { a0 = b0; a1 = b1; a2 = b2; a3 = b3; }
    }
    sigma += __shfl_xor(sigma, 1);
    if (hh == 0) outT[(size_t)j * NPTS + s] = (_Float16)fmaxf(sigma, 0.0f);
}

// ---------------- finalize: out[perm[s]][j] = outT[j][s], f32 ----------------

__global__ __launch_bounds__(256) void finalize_k(
    const _Float16* __restrict__ outT, const int* __restrict__ perm,
    float* __restrict__ out)
{
    const int s = blockIdx.x * 256 + threadIdx.x;
    const int n = perm[s];
    float4 o[6];
#pragma unroll
    for (int j = 0; j < NJ; ++j)                       // strided-coalesced reads
        ((float*)o)[j] = (float)outT[(size_t)j * NPTS + s];
    float4* dst = (float4*)(out + (size_t)n * NJ);     // 96B contiguous, 16B-aligned
#pragma unroll
    for (int k = 0; k < 6; ++k) dst[k] = o[k];
}

// ---------------- fallback (ws too small): round-3 scalar kernel ----------------

__global__ __launch_bounds__(256) void simple_trisample_k(
    const float* __restrict__ xyz, const float* __restrict__ Tm,
    const float* __restrict__ p0, const float* __restrict__ p1,
    const float* __restrict__ p2, const float* __restrict__ l0,
    const float* __restrict__ l1, const float* __restrict__ l2,
    float* __restrict__ out)
{
    const int tid = blockIdx.x * 256 + threadIdx.x;
    const int j = tid >> 18;
    const int n = tid & (NPTS - 1);
    const float x = xyz[3*n+0], y = xyz[3*n+1], z = xyz[3*n+2];
    const float* Tj = Tm + 16*j;
    float g[3];
#pragma unroll
    for (int a = 0; a < 3; ++a) {
        const float pt = Tj[4*a+0]*x + Tj[4*a+1]*y + Tj[4*a+2]*z + Tj[4*a+3];
        g[a] = (pt + 1.5f) * (2.0f/3.0f) - 1.0f;
    }
    const float* P[3] = {p0, p1, p2};
    const float* L[3] = {l0, l1, l2};
    const int M0[3] = {0,0,1}, M1[3] = {1,2,2}, MV[3] = {2,1,0};
    float sigma = 0.0f;
#pragma unroll
    for (int p = 0; p < 3; ++p) {
        const float ix = (g[M0[p]] + 1.0f) * 63.5f;
        const float iy = (g[M1[p]] + 1.0f) * 63.5f;
        const float iz = (g[MV[p]] + 1.0f) * 63.5f;
        const float fx = floorf(ix), fy = floorf(iy), fz = floorf(iz);
        const int x0 = (int)fx, y0 = (int)fy, z0 = (int)fz;
        const float wx1 = ix - fx, wy1 = iy - fy, wz1 = iz - fz;
        const float mx0 = (x0   >= 0 && x0   < NG) ? (1.0f - wx1) : 0.0f;
        const float mx1 = (x0+1 >= 0 && x0+1 < NG) ? wx1 : 0.0f;
        const float my0 = (y0   >= 0 && y0   < NG) ? (1.0f - wy1) : 0.0f;
        const float my1 = (y0+1 >= 0 && y0+1 < NG) ? wy1 : 0.0f;
        const float mz0 = (z0   >= 0 && z0   < NG) ? (1.0f - wz1) : 0.0f;
        const float mz1 = (z0+1 >= 0 && z0+1 < NG) ? wz1 : 0.0f;
        const int xc0 = min(max(x0,0),NG-1), xc1 = min(max(x0+1,0),NG-1);
        const int yc0 = min(max(y0,0),NG-1), yc1 = min(max(y0+1,0),NG-1);
        const int zc0 = min(max(z0,0),NG-1), zc1 = min(max(z0+1,0),NG-1);
        const float w00 = mx0*my0, w01 = mx1*my0, w10 = mx0*my1, w11 = mx1*my1;
        const int o00 = yc0*NG+xc0, o01 = yc0*NG+xc1, o10 = yc1*NG+xc0, o11 = yc1*NG+xc1;
        const float* pb = P[p] + (size_t)j * NC * NG * NG;
        const float* lb = L[p] + (size_t)j * NC * NG;
#pragma unroll 4
        for (int c = 0; c < NC; ++c) {
            const float* pc = pb + (size_t)c * NG * NG;
            const float pf = pc[o00]*w00 + pc[o01]*w01 + pc[o10]*w10 + pc[o11]*w11;
            const float* lc = lb + (size_t)c * NG;
            sigma += pf * (lc[zc0]*mz0 + lc[zc1]*mz1);
        }
    }
    out[(size_t)n * NJ + j] = fmaxf(sigma, 0.0f);
}

// ---------------- launch ----------------

extern "C" void kernel_launch(void* const* d_in, const int* in_sizes, int n_in,
                              void* d_out, int out_size, void* d_ws, size_t ws_size,
                              hipStream_t stream) {
    const float* xyz = nullptr;
    const float* Tm  = nullptr;
    const float* P[3] = {nullptr, nullptr, nullptr};
    const float* L[3] = {nullptr, nullptr, nullptr};
    int pi = 0, li = 0;
    for (int i = 0; i < n_in; ++i) {
        const int si = in_sizes[i];
        if      (si == NPTS * 3)            xyz = (const float*)d_in[i];
        else if (si == 16 * NJ)             Tm  = (const float*)d_in[i];
        else if (si == NJ * NC * NG * NG) { if (pi < 3) P[pi++] = (const float*)d_in[i]; }
        else if (si == NJ * NC * NG)      { if (li < 3) L[li++] = (const float*)d_in[i]; }
    }
    if (!xyz || !Tm || pi != 3 || li != 3) {
        xyz = (const float*)d_in[0];  Tm = (const float*)d_in[1];
        P[0] = (const float*)d_in[2]; P[1] = (const float*)d_in[3];
        P[2] = (const float*)d_in[4];
        L[0] = (const float*)d_in[5]; L[1] = (const float*)d_in[6];
        L[2] = (const float*)d_in[7];
    }
    float* out = (float*)d_out;
    char*  ws  = (char*)d_ws;

    if (ws_size >= WS_NEED) {
        _Float16* wsP   = (_Float16*)(ws + OFF_WSP);
        _Float16* wsL   = (_Float16*)(ws + OFF_WSL);
        _Float16* outT  = (_Float16*)(ws + OFF_OUTT);
        int*      perm  = (int*)     (ws + OFF_PERM);
        float*    xyzS  = (float*)   (ws + OFF_XYZS);
        int*      hist  = (int*)     (ws + OFF_HIST);
        int*      cur   = (int*)     (ws + OFF_CUR);

        hipMemsetAsync(hist, 0, (size_t)2 * NBIN * sizeof(int), stream);  // hist+cur
        transpose_planes_c2<<<dim3(NG/4, NJ, 3), 256, 0, stream>>>(P[0], P[1], P[2], wsP);
        transpose_lines_h<<<dim3(LSZ/256, 1, 3), 256, 0, stream>>>(L[0], L[1], L[2], wsL);
        hist_k<<<NPTS/256, 256, 0, stream>>>(xyz, hist);
        scan_k<<<1, 256, 0, stream>>>(hist, cur);
        scatter_k<<<NPTS/256, 256, 0, stream>>>(xyz, cur, perm, xyzS);
        trisample_m_k<<<6144, 256, 0, stream>>>(xyzS, Tm, wsP, wsL, outT);
        finalize_k<<<NPTS/256, 256, 0, stream>>>(outT, perm, out);
    } else {
        simple_trisample_k<<<(NPTS*NJ)/256, 256, 0, stream>>>(xyz, Tm, P[0], P[1], P[2],
                                                              L[0], L[1], L[2], out);
    }
}

// Round 13
// 177.664 us; speedup vs baseline: 1.3815x; 1.0192x over previous
//
#include <hip/hip_runtime.h>
#include <hip/hip_fp16.h>

#define NPTS 262144
#define NJ   24
#define NC   16
#define NG   128
#define PSZ  (NJ*NG*NG*NC)   // halfs per transposed plane
#define LSZ  (NJ*NG*NC)      // halfs per transposed line set
#define NBIN 32768           // 32^3 Morton bins

typedef _Float16 h2 __attribute__((ext_vector_type(2)));
typedef _Float16 h8 __attribute__((ext_vector_type(8)));

static __device__ __forceinline__ h8 splat8(float w) {
    _Float16 h = (_Float16)w;
    return (h8){h,h,h,h,h,h,h,h};
}

// ---- ws layout (bytes): all 16B-aligned ----
#define OFF_WSP   ((size_t)0)
#define OFF_WSL   (OFF_WSP + (size_t)3*PSZ*2)
#define OFF_OUTT  (OFF_WSL + (size_t)3*LSZ*2)                 // fp16 [J][NPTS]
#define OFF_PERM  (OFF_OUTT + (size_t)NJ*NPTS*2)              // int  [NPTS]
#define OFF_XYZS  (OFF_PERM + (size_t)NPTS*4)                 // f32  [NPTS][4]
#define OFF_HIST  (OFF_XYZS + (size_t)NPTS*16)                // int  [NBIN]
#define OFF_CUR   (OFF_HIST + (size_t)NBIN*4)                 // int  [NBIN]
#define WS_NEED   (OFF_CUR + (size_t)NBIN*4)

// ---------------- Morton bin key (32^3) ----------------

static __device__ __forceinline__ int bin_key(float x, float y, float z) {
    const int qx = min(max((int)((x + 1.0f) * 16.0f), 0), 31);
    const int qy = min(max((int)((y + 1.0f) * 16.0f), 0), 31);
    const int qz = min(max((int)((z + 1.0f) * 16.0f), 0), 31);
    int k = 0;
#pragma unroll
    for (int b = 0; b < 5; ++b) {
        k |= (((qx >> b) & 1) << (3*b + 2))
           | (((qy >> b) & 1) << (3*b + 1))
           | (((qz >> b) & 1) << (3*b));
    }
    return k;
}

// -------- fused prep: plane transpose (c2) + line transpose + hist in ONE kernel ------
// Independent passes; fusing co-schedules BW-bound transpose blocks with
// atomic-bound hist blocks and saves 2 launch gaps (hipEvent* fork is banned).

#define PB_P 2304   // 3 planes * 24 j * 32 y-blocks
#define PB_L 576    // 3 planes * 192
#define PB_H 1024   // NPTS/256
#define PB_TOT (PB_P + PB_L + PB_H)

__global__ __launch_bounds__(256) void prep_k(
    const float* __restrict__ p0, const float* __restrict__ p1,
    const float* __restrict__ p2, const float* __restrict__ l0,
    const float* __restrict__ l1, const float* __restrict__ l2,
    const float* __restrict__ xyz, _Float16* __restrict__ wsP,
    _Float16* __restrict__ wsL, int* __restrict__ hist)
{
    const int b = blockIdx.x;
    if (b < PB_P) {
        // plane transpose: f32 [J][C][G][G] -> fp16 [J][G][G][C], float2 reads
        const int p   = b / 768;
        const int rem = b % 768;
        const int j   = rem >> 5;
        const int x = (threadIdx.x & 63) * 2;
        const int y = (rem & 31) * 4 + (threadIdx.x >> 6);
        const float* src = ((p == 0) ? p0 : (p == 1) ? p1 : p2)
                         + ((size_t)j * NC * NG + y) * NG + x;
        float2 v[16];
#pragma unroll
        for (int c = 0; c < NC; ++c)
            v[c] = *(const float2*)(src + (size_t)c * NG * NG);
        _Float16* dst = wsP + (size_t)p * PSZ + (size_t)((j * NG + y) * NG + x) * NC;
        *(h8*)(dst)      = (h8){(_Float16)v[0].x,(_Float16)v[1].x,(_Float16)v[2].x,(_Float16)v[3].x,
                                (_Float16)v[4].x,(_Float16)v[5].x,(_Float16)v[6].x,(_Float16)v[7].x};
        *(h8*)(dst + 8)  = (h8){(_Float16)v[8].x,(_Float16)v[9].x,(_Float16)v[10].x,(_Float16)v[11].x,
                                (_Float16)v[12].x,(_Float16)v[13].x,(_Float16)v[14].x,(_Float16)v[15].x};
        *(h8*)(dst + 16) = (h8){(_Float16)v[0].y,(_Float16)v[1].y,(_Float16)v[2].y,(_Float16)v[3].y,
                                (_Float16)v[4].y,(_Float16)v[5].y,(_Float16)v[6].y,(_Float16)v[7].y};
        *(h8*)(dst + 24) = (h8){(_Float16)v[8].y,(_Float16)v[9].y,(_Float16)v[10].y,(_Float16)v[11].y,
                                (_Float16)v[12].y,(_Float16)v[13].y,(_Float16)v[14].y,(_Float16)v[15].y};
    } else if (b < PB_P + PB_L) {
        // line transpose: f32 [J][C][G] -> fp16 [J][G][C]
        const int t = b - PB_P;
        const int p = t / 192;
        const int idx = (t % 192) * 256 + threadIdx.x;   // [0, LSZ)
        const int c = idx & 15;
        const int z = (idx >> 4) & 127;
        const int j = idx >> 11;
        const float* src = (p == 0) ? l0 : (p == 1) ? l1 : l2;
        wsL[(size_t)p * LSZ + (size_t)(j * NG + z) * NC + c] =
            (_Float16)src[(j * NC + c) * NG + z];
    } else {
        // histogram over Morton bins
        const int n = (b - PB_P - PB_L) * 256 + threadIdx.x;
        atomicAdd(&hist[bin_key(xyz[3*n], xyz[3*n+1], xyz[3*n+2])], 1);
    }
}

// exclusive prefix over 32768 bins: 256 threads x 128 bins each
__global__ __launch_bounds__(256) void scan_k(
    const int* __restrict__ hist, int* __restrict__ cursor)
{
    __shared__ int ssum[256];
    const int tid = threadIdx.x;
    const int base = tid * 128;
    int s = 0;
    for (int k = 0; k < 128; ++k) s += hist[base + k];
    ssum[tid] = s;
    __syncthreads();
    for (int off = 1; off < 256; off <<= 1) {       // Hillis-Steele inclusive
        int v = (tid >= off) ? ssum[tid - off] : 0;
        __syncthreads();
        ssum[tid] += v;
        __syncthreads();
    }
    int run = (tid == 0) ? 0 : ssum[tid - 1];       // exclusive base
    for (int k = 0; k < 128; ++k) {
        cursor[base + k] = run;
        run += hist[base + k];
    }
}

__global__ __launch_bounds__(256) void scatter_k(
    const float* __restrict__ xyz, int* __restrict__ cursor,
    int* __restrict__ perm, float* __restrict__ xyzS /* [NPTS][4] */)
{
    const int n = blockIdx.x * 256 + threadIdx.x;
    const float x = xyz[3*n], y = xyz[3*n+1], z = xyz[3*n+2];
    const int pos = atomicAdd(&cursor[bin_key(x, y, z)], 1);
    perm[pos] = n;
    *(float4*)(xyzS + 4*(size_t)pos) = make_float4(x, y, z, 0.0f);
}

// ---------- main kernel: 2 lanes/pair, 8 chunks/block, unroll 4 ----------

__global__ __launch_bounds__(256) void trisample_m_k(
    const float* __restrict__ xyzS, const float* __restrict__ Tm,
    const _Float16* __restrict__ wsP, const _Float16* __restrict__ wsL,
    _Float16* __restrict__ outT /* fp16 [J][NPTS] */)
{
    __shared__ _Float16 sL[3 * NG * NC];    // 12 KB: this block's joint line data

    // Bijective XCD swizzle: 6144 = 8*768 -> XCD k owns joints [3k, 3k+3).
    const int sb = (blockIdx.x & 7) * 768 + (blockIdx.x >> 3);
    const int j  = sb >> 8;                    // 256 blocks per joint
    const int g0 = (sb & 255) << 10;           // 1024 sorted points per block

    {   // stage line data ONCE: 3 planes x 4KB
        uint4* s4 = (uint4*)sL;
#pragma unroll
        for (int k = 0; k < 3; ++k) {
            const int idx = k * 256 + threadIdx.x;
            const int p = idx >> 8, r = idx & 255;
            s4[idx] = ((const uint4*)(wsL + (size_t)p * LSZ + (size_t)j * (NG*NC)))[r];
        }
    }
    __syncthreads();

    const int sbase = g0 + (threadIdx.x >> 1);
    const int hh    = (threadIdx.x & 1) << 3;  // channel offset 0 or 8
    const float* Tj = Tm + 16*j;               // uniform within block -> scalar loads
    const int M0[3] = {0,0,1}, M1[3] = {1,2,2}, MV[3] = {2,1,0};

    const _Float16* pjbase[3];
#pragma unroll
    for (int p = 0; p < 3; ++p)
        pjbase[p] = wsP + (size_t)p * PSZ + (size_t)j * (NG*NG*NC) + hh;

#pragma unroll 4
    for (int ch = 0; ch < 8; ++ch) {
        const int s = sbase + (ch << 7);       // 128 pairs per chunk

        const float4 pv = *(const float4*)(xyzS + 4*(size_t)s);
        const float px = pv.x, py = pv.y, pz = pv.z;

        float m0[3], m1[3];
        int   c0[3], c1[3];
#pragma unroll
        for (int a = 0; a < 3; ++a) {
            const float pt = fmaf(Tj[4*a+0], px,
                              fmaf(Tj[4*a+1], py,
                               fmaf(Tj[4*a+2], pz, Tj[4*a+3])));
            const float ia = fmaf(pt, 127.0f/3.0f, 63.5f);  // folded normalize+scale
            const float fa = floorf(ia);
            const int   i0 = (int)fa;
            const float w1 = ia - fa;
            m0[a] = (i0 >=  0 && i0 < NG    ) ? (1.0f - w1) : 0.0f;
            m1[a] = (i0 >= -1 && i0 < NG - 1) ? w1          : 0.0f;
            c0[a] = min(max(i0,     0), NG-1);
            c1[a] = min(max(i0 + 1, 0), NG-1);
        }

        int rb0[3], rb1[3], cb0[3], cb1[3];
#pragma unroll
        for (int p = 0; p < 3; ++p) {
            rb0[p] = c0[M1[p]] * (NG*NC);  rb1[p] = c1[M1[p]] * (NG*NC);
            cb0[p] = c0[M0[p]] * NC;       cb1[p] = c1[M0[p]] * NC;
        }

        float sigma = 0.0f;
        h8 a0 = *(const h8*)(pjbase[0] + rb0[0] + cb0[0]);
        h8 a1 = *(const h8*)(pjbase[0] + rb0[0] + cb1[0]);
        h8 a2 = *(const h8*)(pjbase[0] + rb1[0] + cb0[0]);
        h8 a3 = *(const h8*)(pjbase[0] + rb1[0] + cb1[0]);
#pragma unroll
        for (int p = 0; p < 3; ++p) {
            h8 b0, b1, b2, b3;
            if (p < 2) {
                b0 = *(const h8*)(pjbase[p+1] + rb0[p+1] + cb0[p+1]);
                b1 = *(const h8*)(pjbase[p+1] + rb0[p+1] + cb1[p+1]);
                b2 = *(const h8*)(pjbase[p+1] + rb1[p+1] + cb0[p+1]);
                b3 = *(const h8*)(pjbase[p+1] + rb1[p+1] + cb1[p+1]);
            }
            const int A = M0[p], B = M1[p], V = MV[p];
            const h8 u0 = *(const h8*)(sL + (p * NG + c0[V]) * NC + hh);
            const h8 u1 = *(const h8*)(sL + (p * NG + c1[V]) * NC + hh);

            h8 pf = a0 * splat8(m0[A] * m0[B]);
            pf += a1 * splat8(m1[A] * m0[B]);
            pf += a2 * splat8(m0[A] * m1[B]);
            pf += a3 * splat8(m1[A] * m1[B]);
            h8 lf = u0 * splat8(m0[V]);
            lf += u1 * splat8(m1[V]);

#if __has_builtin(__builtin_amdgcn_fdot2)
#pragma unroll
            for (int q = 0; q < 4; ++q) {
                const h2 va = {pf[2*q], pf[2*q+1]};
                const h2 vb = {lf[2*q], lf[2*q+1]};
                sigma = __builtin_amdgcn_fdot2(va, vb, sigma, false);
            }
#else
#pragma unroll
            for (int q = 0; q < 8; ++q)
                sigma += (float)pf[q] * (float)lf[q];
#endif
            if (p < 2) { a0 = b0; a1 = b1; a2 = b2; a3 = b3; }
        }

        sigma += __shfl_xor(sigma, 1);
        if (hh == 0)
            outT[(size_t)j * NPTS + s] = (_Float16)fmaxf(sigma, 0.0f);
    }
}

// ---------------- finalize: out[perm[s]][j] = outT[j][s], f32 ----------------

__global__ __launch_bounds__(256) void finalize_k(
    const _Float16* __restrict__ outT, const int* __restrict__ perm,
    float* __restrict__ out)
{
    const int s = blockIdx.x * 256 + threadIdx.x;
    const int n = perm[s];
    float4 o[6];
#pragma unroll
    for (int j = 0; j < NJ; ++j)                       // strided-coalesced reads
        ((float*)o)[j] = (float)outT[(size_t)j * NPTS + s];
    float4* dst = (float4*)(out + (size_t)n * NJ);     // 96B contiguous, 16B-aligned
#pragma unroll
    for (int k = 0; k < 6; ++k) dst[k] = o[k];
}

// ---------------- fallback (ws too small): round-3 scalar kernel ----------------

__global__ __launch_bounds__(256) void simple_trisample_k(
    const float* __restrict__ xyz, const float* __restrict__ Tm,
    const float* __restrict__ p0, const float* __restrict__ p1,
    const float* __restrict__ p2, const float* __restrict__ l0,
    const float* __restrict__ l1, const float* __restrict__ l2,
    float* __restrict__ out)
{
    const int tid = blockIdx.x * 256 + threadIdx.x;
    const int j = tid >> 18;
    const int n = tid & (NPTS - 1);
    const float x = xyz[3*n+0], y = xyz[3*n+1], z = xyz[3*n+2];
    const float* Tj = Tm + 16*j;
    float g[3];
#pragma unroll
    for (int a = 0; a < 3; ++a) {
        const float pt = Tj[4*a+0]*x + Tj[4*a+1]*y + Tj[4*a+2]*z + Tj[4*a+3];
        g[a] = (pt + 1.5f) * (2.0f/3.0f) - 1.0f;
    }
    const float* P[3] = {p0, p1, p2};
    const float* L[3] = {l0, l1, l2};
    const int M0[3] = {0,0,1}, M1[3] = {1,2,2}, MV[3] = {2,1,0};
    float sigma = 0.0f;
#pragma unroll
    for (int p = 0; p < 3; ++p) {
        const float ix = (g[M0[p]] + 1.0f) * 63.5f;
        const float iy = (g[M1[p]] + 1.0f) * 63.5f;
        const float iz = (g[MV[p]] + 1.0f) * 63.5f;
        const float fx = floorf(ix), fy = floorf(iy), fz = floorf(iz);
        const int x0 = (int)fx, y0 = (int)fy, z0 = (int)fz;
        const float wx1 = ix - fx, wy1 = iy - fy, wz1 = iz - fz;
        const float mx0 = (x0   >= 0 && x0   < NG) ? (1.0f - wx1) : 0.0f;
        const float mx1 = (x0+1 >= 0 && x0+1 < NG) ? wx1 : 0.0f;
        const float my0 = (y0   >= 0 && y0   < NG) ? (1.0f - wy1) : 0.0f;
        const float my1 = (y0+1 >= 0 && y0+1 < NG) ? wy1 : 0.0f;
        const float mz0 = (z0   >= 0 && z0   < NG) ? (1.0f - wz1) : 0.0f;
        const float mz1 = (z0+1 >= 0 && z0+1 < NG) ? wz1 : 0.0f;
        const int xc0 = min(max(x0,0),NG-1), xc1 = min(max(x0+1,0),NG-1);
        const int yc0 = min(max(y0,0),NG-1), yc1 = min(max(y0+1,0),NG-1);
        const int zc0 = min(max(z0,0),NG-1), zc1 = min(max(z0+1,0),NG-1);
        const float w00 = mx0*my0, w01 = mx1*my0, w10 = mx0*my1, w11 = mx1*my1;
        const int o00 = yc0*NG+xc0, o01 = yc0*NG+xc1, o10 = yc1*NG+xc0, o11 = yc1*NG+xc1;
        const float* pb = P[p] + (size_t)j * NC * NG * NG;
        const float* lb = L[p] + (size_t)j * NC * NG;
#pragma unroll 4
        for (int c = 0; c < NC; ++c) {
            const float* pc = pb + (size_t)c * NG * NG;
            const float pf = pc[o00]*w00 + pc[o01]*w01 + pc[o10]*w10 + pc[o11]*w11;
            const float* lc = lb + (size_t)c * NG;
            sigma += pf * (lc[zc0]*mz0 + lc[zc1]*mz1);
        }
    }
    out[(size_t)n * NJ + j] = fmaxf(sigma, 0.0f);
}

// ---------------- launch ----------------

extern "C" void kernel_launch(void* const* d_in, const int* in_sizes, int n_in,
                              void* d_out, int out_size, void* d_ws, size_t ws_size,
                              hipStream_t stream) {
    const float* xyz = nullptr;
    const float* Tm  = nullptr;
    const float* P[3] = {nullptr, nullptr, nullptr};
    const float* L[3] = {nullptr, nullptr, nullptr};
    int pi = 0, li = 0;
    for (int i = 0; i < n_in; ++i) {
        const int si = in_sizes[i];
        if      (si == NPTS * 3)            xyz = (const float*)d_in[i];
        else if (si == 16 * NJ)             Tm  = (const float*)d_in[i];
        else if (si == NJ * NC * NG * NG) { if (pi < 3) P[pi++] = (const float*)d_in[i]; }
        else if (si == NJ * NC * NG)      { if (li < 3) L[li++] = (const float*)d_in[i]; }
    }
    if (!xyz || !Tm || pi != 3 || li != 3) {
        xyz = (const float*)d_in[0];  Tm = (const float*)d_in[1];
        P[0] = (const float*)d_in[2]; P[1] = (const float*)d_in[3];
        P[2] = (const float*)d_in[4];
        L[0] = (const float*)d_in[5]; L[1] = (const float*)d_in[6];
        L[2] = (const float*)d_in[7];
    }
    float* out = (float*)d_out;
    char*  ws  = (char*)d_ws;

    if (ws_size >= WS_NEED) {
        _Float16* wsP   = (_Float16*)(ws + OFF_WSP);
        _Float16* wsL   = (_Float16*)(ws + OFF_WSL);
        _Float16* outT  = (_Float16*)(ws + OFF_OUTT);
        int*      perm  = (int*)     (ws + OFF_PERM);
        float*    xyzS  = (float*)   (ws + OFF_XYZS);
        int*      hist  = (int*)     (ws + OFF_HIST);
        int*      cur   = (int*)     (ws + OFF_CUR);

        hipMemsetAsync(hist, 0, (size_t)2 * NBIN * sizeof(int), stream);  // hist+cur
        prep_k<<<PB_TOT, 256, 0, stream>>>(P[0], P[1], P[2], L[0], L[1], L[2],
                                           xyz, wsP, wsL, hist);
        scan_k<<<1, 256, 0, stream>>>(hist, cur);
        scatter_k<<<NPTS/256, 256, 0, stream>>>(xyz, cur, perm, xyzS);
        trisample_m_k<<<6144, 256, 0, stream>>>(xyzS, Tm, wsP, wsL, outT);
        finalize_k<<<NPTS/256, 256, 0, stream>>>(outT, perm, out);
    } else {
        simple_trisample_k<<<(NPTS*NJ)/256, 256, 0, stream>>>(xyz, Tm, P[0], P[1], P[2],
                                                              L[0], L[1], L[2], out);
    }
}